// Round 8
// baseline (586.234 us; speedup 1.0000x reference)
//
#include <hip/hip_runtime.h>
#include <hip/hip_fp16.h>

// imgs (8,3,1024,1024) fp32, z (1e6,2) fp32 -> out (8,2) fp32.
// R19 (this round): LDS-free barrier-free sweep + 3 dispatches.
//   - sweep: no T-table write means no thread<->column transpose is needed
//     (that transpose was only ever for coalesced 64B record stores). Each
//     thread keeps its 4 loaded columns x 2 batches, gets the next-column S
//     via ONE __shfl_down per row (lane 63 uses the strip-edge sum), decodes
//     4 hist cells, does 16 cell-FMAs, wave-reduces, lane0 fires 4 atomics.
//     Zero LDS, zero barriers -> no vmcnt-drain serialization, occupancy
//     VGPR-limited only.
//   - zero_hist kernel replaced by hipMemsetAsync (stream-capturable);
//     out[16] zeroing folded into hist_kernel block 0. Dispatches 4 -> 3.
//   - hist unchanged from R18: 1 u64 fixed-point atomic per point
//     {cnt:12b | sumU:26b | sumV:26b}, u/v quantized 2^-20.
//   Per cell: sum(gc0) = cnt*Dy + sumU*M ; sum(gc1) = cnt*Dx + sumV*M.

#define NYX 1024
#define NPIX (NYX * NYX)
#define BATCH 8
#define CH 3
#define QSCALE 1048576.0f                            // 2^20
#define QINV   (1.0f / 1048576.0f)

// ---- 1) point histogram: ONE u64 atomic per point ----
__device__ __forceinline__ void hist_pt(float zy, float zx,
                                        unsigned long long* __restrict__ hist)
{
    float x0y = zy * (float)(NYX - 1);
    float x0x = zx * (float)(NYX - 1);
    bool oob = (x0y < 0.0f) || (x0y > (float)(NYX - 1)) ||
               (x0x < 0.0f) || (x0x > (float)(NYX - 1));
    if (oob) return;                                 // contributes nothing
    int yg = min((int)x0y, NYX - 2);
    int xg = min((int)x0x, NYX - 2);
    float u = x0x - (float)xg;
    float v = x0y - (float)yg;
    unsigned qu = (unsigned)(u * QSCALE + 0.5f);     // <= 2^20, fits 26b
    unsigned qv = (unsigned)(v * QSCALE + 0.5f);
    unsigned long long key = (1ULL << 52) |
                             ((unsigned long long)qu << 26) |
                             (unsigned long long)qv;
    atomicAdd(&hist[(yg << 10) + xg], key);          // fire-and-forget
}

__global__ __launch_bounds__(256) void hist_kernel(
    const float* __restrict__ z, unsigned long long* __restrict__ hist,
    float* __restrict__ out, int npts)
{
    int i = blockIdx.x * 256 + threadIdx.x;
    if (blockIdx.x == 0 && threadIdx.x < 16)
        out[threadIdx.x] = 0.0f;                     // zero before sweep runs
    int npairs = npts >> 1;
    if (i < npairs) {
        float4 zz = ((const float4*)z)[i];
        hist_pt(zz.x, zz.y, hist);
        hist_pt(zz.z, zz.w, hist);
    } else if (i == npairs && (npts & 1)) {          // odd tail point
        hist_pt(z[2 * npts - 2], z[2 * npts - 1], hist);
    }
}

// ---- 2) LDS-free image sweep ----
__device__ __forceinline__ void dec_cell(unsigned lo, unsigned hi,
                                         float& cnt, float& su, float& sv)
{
    cnt = (float)(hi >> 20);                         // bits 52..63
    su  = (float)((lo >> 26) | ((hi & 0xFFFFFu) << 6)) * QINV;  // bits 26..51
    sv  = (float)(lo & 0x3FFFFFFu) * QINV;           // bits 0..25
}

__global__ __launch_bounds__(256, 4) void sweep_kernel(
    const float* __restrict__ imgs, const uint4* __restrict__ hist2,
    float* __restrict__ out)
{
    // 2048 blocks. XCD swizzle (R13): chunk of 256 logical blocks per XCD,
    // y-major within a strip so adjacent y-groups (sharing boundary row
    // y0+2) are dispatched back-to-back on the same XCD.
    int bid0  = blockIdx.x;
    int L     = ((bid0 & 7) << 8) | (bid0 >> 3);     // bijective on [0,2048)
    int ygrp  = L & 511;
    int strip = L >> 9;                              // 0..3
    int y0    = ygrp << 1;
    int x0    = strip << 8;
    int t     = threadIdx.x;
    int l     = t & 63;
    int g     = t >> 6;                              // group -> batches 2g,2g+1
    int xe    = min(x0 + 256, NYX - 1);              // strip-edge col

    int yr[3] = { y0, min(y0 + 1, NYX - 1), min(y0 + 2, NYX - 1) };

    // hist rows y0, y0+1, cols x0+4l..x0+4l+3 (u64 pairs as uint4), 32 B/lane
    size_t hb0 = ((size_t)y0 * NYX + x0 + 4 * l) >> 1;        // uint4 index
    size_t hb1 = ((size_t)(y0 + 1) * NYX + x0 + 4 * l) >> 1;
    uint4 h0a = hist2[hb0], h0b = hist2[hb0 + 1];
    uint4 h1a = hist2[hb1], h1b = hist2[hb1 + 1];

    // 18 image float4 loads, channel-summed -> S[r][bl][0..3] (cols 4l..4l+3)
    float S[3][2][4];
#pragma unroll
    for (int r = 0; r < 3; ++r) {
#pragma unroll
        for (int bl = 0; bl < 2; ++bl) {
            int b = 2 * g + bl;
            size_t q = (size_t)yr[r] * NYX + x0;
            float4 a0 = ((const float4*)(imgs + (size_t)(b * CH + 0) * NPIX + q))[l];
            float4 a1 = ((const float4*)(imgs + (size_t)(b * CH + 1) * NPIX + q))[l];
            float4 a2 = ((const float4*)(imgs + (size_t)(b * CH + 2) * NPIX + q))[l];
            S[r][bl][0] = a0.x + a1.x + a2.x;
            S[r][bl][1] = a0.y + a1.y + a2.y;
            S[r][bl][2] = a0.z + a1.z + a2.z;
            S[r][bl][3] = a0.w + a1.w + a2.w;
        }
    }

    // strip-edge column (only meaningful for lane 63)
    float edge[3][2] = {{0.f,0.f},{0.f,0.f},{0.f,0.f}};
    if (l == 63) {
#pragma unroll
        for (int r = 0; r < 3; ++r) {
#pragma unroll
            for (int bl = 0; bl < 2; ++bl) {
                int b = 2 * g + bl;
                size_t qe = (size_t)yr[r] * NYX + xe;
                edge[r][bl] = imgs[(size_t)(b * CH + 0) * NPIX + qe] +
                              imgs[(size_t)(b * CH + 1) * NPIX + qe] +
                              imgs[(size_t)(b * CH + 2) * NPIX + qe];
            }
        }
    }

    // next-column S via cross-lane shuffle (lane 63 <- edge)
    float sp[3][2];
#pragma unroll
    for (int r = 0; r < 3; ++r) {
#pragma unroll
        for (int bl = 0; bl < 2; ++bl) {
            float nx = __shfl_down(S[r][bl][0], 1, 64);
            sp[r][bl] = (l == 63) ? edge[r][bl] : nx;
        }
    }

    // decode 8 hist cells once (batch-independent)
    float cnt[2][4], su[2][4], sv[2][4];
    dec_cell(h0a.x, h0a.y, cnt[0][0], su[0][0], sv[0][0]);
    dec_cell(h0a.z, h0a.w, cnt[0][1], su[0][1], sv[0][1]);
    dec_cell(h0b.x, h0b.y, cnt[0][2], su[0][2], sv[0][2]);
    dec_cell(h0b.z, h0b.w, cnt[0][3], su[0][3], sv[0][3]);
    dec_cell(h1a.x, h1a.y, cnt[1][0], su[1][0], sv[1][0]);
    dec_cell(h1a.z, h1a.w, cnt[1][1], su[1][1], sv[1][1]);
    dec_cell(h1b.x, h1b.y, cnt[1][2], su[1][2], sv[1][2]);
    dec_cell(h1b.z, h1b.w, cnt[1][3], su[1][3], sv[1][3]);

    // 16 cells per batch-lane: rows k=0,1 x cols j=0..3 x batches bl=0,1
    float acc0[2] = {0.f, 0.f}, acc1[2] = {0.f, 0.f};
#pragma unroll
    for (int bl = 0; bl < 2; ++bl) {
#pragma unroll
        for (int k = 0; k < 2; ++k) {
#pragma unroll
            for (int j = 0; j < 4; ++j) {
                float c00 = S[k][bl][j];
                float c01 = (j < 3) ? S[k][bl][j + 1] : sp[k][bl];
                float c10 = S[k + 1][bl][j];
                float c11 = (j < 3) ? S[k + 1][bl][j + 1] : sp[k + 1][bl];
                float Dy = c10 - c00;
                float Dx = c01 - c00;
                float Mm = (c11 - c01) - Dy;
                acc0[bl] += cnt[k][j] * Dy + su[k][j] * Mm;
                acc1[bl] += cnt[k][j] * Dx + sv[k][j] * Mm;
            }
        }
    }

    // wave reduction, then 4 atomics from lane 0 (batches 2g, 2g+1)
#pragma unroll
    for (int off = 32; off > 0; off >>= 1) {
        acc0[0] += __shfl_down(acc0[0], off, 64);
        acc1[0] += __shfl_down(acc1[0], off, 64);
        acc0[1] += __shfl_down(acc0[1], off, 64);
        acc1[1] += __shfl_down(acc1[1], off, 64);
    }
    if (l == 0) {
        int b0 = 2 * g;
        atomicAdd(&out[2 * b0 + 0], acc0[0]);
        atomicAdd(&out[2 * b0 + 1], acc1[0]);
        atomicAdd(&out[2 * b0 + 2], acc0[1]);
        atomicAdd(&out[2 * b0 + 3], acc1[1]);
    }
}

// ---- fallback (round-1 unsorted path) if ws is too small ----
__global__ void zero_out_kernel(float* __restrict__ out) {
    int i = threadIdx.x;
    if (i < 16) out[i] = 0.0f;
}

__global__ __launch_bounds__(256) void interp_grad_kernel(
    const float* __restrict__ imgs, const float* __restrict__ z,
    float* __restrict__ out, int npts)
{
    int p = blockIdx.x * blockDim.x + threadIdx.x;
    float acc0[BATCH];
    float acc1[BATCH];
#pragma unroll
    for (int b = 0; b < BATCH; ++b) { acc0[b] = 0.0f; acc1[b] = 0.0f; }
    if (p < npts) {
        float2 zz = ((const float2*)z)[p];
        float x0y = zz.x * (float)(NYX - 1);
        float x0x = zz.y * (float)(NYX - 1);
        bool oob = (x0y < 0.0f) || (x0y > (float)(NYX - 1)) ||
                   (x0x < 0.0f) || (x0x > (float)(NYX - 1));
        if (!oob) {
            int yg = min((int)floorf(x0y), NYX - 2);
            int xg = min((int)floorf(x0x), NYX - 2);
            float fy = (float)yg - x0y;
            float fx = (float)xg - x0x;
            const float* base = imgs + (size_t)yg * NYX + xg;
#pragma unroll
            for (int b = 0; b < BATCH; ++b) {
#pragma unroll
                for (int c = 0; c < CH; ++c) {
                    const float* pl = base + (size_t)(b * CH + c) * (size_t)NPIX;
                    float g00 = pl[0];
                    float g01 = pl[1];
                    float g10 = pl[NYX];
                    float g11 = pl[NYX + 1];
                    float a1 = g10 - g00;
                    float a2 = g11 - g01;
                    float a3 = g01 - g00;
                    float d  = a1 - a2;
                    acc0[b] += d * fx + a1;
                    acc1[b] += d * fy + a3;
                }
            }
        }
    }
#pragma unroll
    for (int b = 0; b < BATCH; ++b) {
#pragma unroll
        for (int off = 32; off > 0; off >>= 1) {
            acc0[b] += __shfl_down(acc0[b], off, 64);
            acc1[b] += __shfl_down(acc1[b], off, 64);
        }
    }
    __shared__ float sred[4][16];
    int lane = threadIdx.x & 63;
    int wave = threadIdx.x >> 6;
    if (lane == 0) {
#pragma unroll
        for (int b = 0; b < BATCH; ++b) {
            sred[wave][2 * b + 0] = acc0[b];
            sred[wave][2 * b + 1] = acc1[b];
        }
    }
    __syncthreads();
    if (threadIdx.x < 16) {
        float s = sred[0][threadIdx.x] + sred[1][threadIdx.x] +
                  sred[2][threadIdx.x] + sred[3][threadIdx.x];
        atomicAdd(&out[threadIdx.x], s);
    }
}

extern "C" void kernel_launch(void* const* d_in, const int* in_sizes, int n_in,
                              void* d_out, int out_size, void* d_ws, size_t ws_size,
                              hipStream_t stream) {
    const float* imgs = (const float*)d_in[0];
    const float* z    = (const float*)d_in[1];
    float* out        = (float*)d_out;
    int npts = in_sizes[1] / 2;

    size_t ws_need = (size_t)NPIX * 8;               // 8 MB u64 hist

    if (ws_size < ws_need) {
        int blocks = (npts + 255) / 256;
        zero_out_kernel<<<1, 64, 0, stream>>>(out);
        interp_grad_kernel<<<blocks, 256, 0, stream>>>(imgs, z, out, npts);
        return;
    }

    unsigned long long* hist = (unsigned long long*)d_ws;
    int npairs = npts >> 1;
    int hist_blocks = (npairs + 256) / 256;          // covers odd-tail thread

    hipMemsetAsync(d_ws, 0, ws_need, stream);        // stream-capturable
    hist_kernel<<<hist_blocks, 256, 0, stream>>>(z, hist, out, npts);
    sweep_kernel<<<2048, 256, 0, stream>>>(imgs, (const uint4*)hist, out);
}

// Round 9
// 202.777 us; speedup vs baseline: 2.8910x; 2.8910x over previous
//
#include <hip/hip_runtime.h>
#include <hip/hip_fp16.h>

// imgs (8,3,1024,1024) fp32, z (1e6,2) fp32 -> out (8,2) fp32.
// R20 (this round): fix the R19 atomic-packet blowup.
//   R19 post-mortem: sweep took 426 us INDEPENDENT of cache state (warm
//   replay identical). Cause: lane0-of-every-wave fired 4 single-lane
//   atomics -> 32768 atomic packets all hitting the ONE 64-B line holding
//   out[0..15]; device-scope ownership of that line ping-pongs across 8
//   XCD L2s per packet. R18's epilogue (LDS block-reduce + ONE 16-lane
//   atomic instruction per block = 2048 packets) measured <58 us.
//   -> keep R19's LDS-free register/shuffle sweep BODY (loads+VALU fine),
//      restore the R18 EPILOGUE: sred[4][4] (64 B LDS), 1 barrier, one
//      16-lane atomic per block.
//   - hist unchanged: 1 u64 fixed-point atomic per point
//     {cnt:12b | sumU:26b | sumV:26b}, u/v quantized 2^-20 (1M packets to
//     1M DIFFERENT lines -> no line contention; measured <58 us in R18).
//   - hipMemsetAsync zeroes hist; out[16] zeroed by hist block 0.
//   Per cell: sum(gc0) = cnt*Dy + sumU*M ; sum(gc1) = cnt*Dx + sumV*M.

#define NYX 1024
#define NPIX (NYX * NYX)
#define BATCH 8
#define CH 3
#define QSCALE 1048576.0f                            // 2^20
#define QINV   (1.0f / 1048576.0f)

// ---- 1) point histogram: ONE u64 atomic per point ----
__device__ __forceinline__ void hist_pt(float zy, float zx,
                                        unsigned long long* __restrict__ hist)
{
    float x0y = zy * (float)(NYX - 1);
    float x0x = zx * (float)(NYX - 1);
    bool oob = (x0y < 0.0f) || (x0y > (float)(NYX - 1)) ||
               (x0x < 0.0f) || (x0x > (float)(NYX - 1));
    if (oob) return;                                 // contributes nothing
    int yg = min((int)x0y, NYX - 2);
    int xg = min((int)x0x, NYX - 2);
    float u = x0x - (float)xg;
    float v = x0y - (float)yg;
    unsigned qu = (unsigned)(u * QSCALE + 0.5f);     // <= 2^20, fits 26b
    unsigned qv = (unsigned)(v * QSCALE + 0.5f);
    unsigned long long key = (1ULL << 52) |
                             ((unsigned long long)qu << 26) |
                             (unsigned long long)qv;
    atomicAdd(&hist[(yg << 10) + xg], key);          // fire-and-forget
}

__global__ __launch_bounds__(256) void hist_kernel(
    const float* __restrict__ z, unsigned long long* __restrict__ hist,
    float* __restrict__ out, int npts)
{
    int i = blockIdx.x * 256 + threadIdx.x;
    if (blockIdx.x == 0 && threadIdx.x < 16)
        out[threadIdx.x] = 0.0f;                     // zero before sweep runs
    int npairs = npts >> 1;
    if (i < npairs) {
        float4 zz = ((const float4*)z)[i];
        hist_pt(zz.x, zz.y, hist);
        hist_pt(zz.z, zz.w, hist);
    } else if (i == npairs && (npts & 1)) {          // odd tail point
        hist_pt(z[2 * npts - 2], z[2 * npts - 1], hist);
    }
}

// ---- 2) image sweep: register body, block-reduced epilogue ----
__device__ __forceinline__ void dec_cell(unsigned lo, unsigned hi,
                                         float& cnt, float& su, float& sv)
{
    cnt = (float)(hi >> 20);                         // bits 52..63
    su  = (float)((lo >> 26) | ((hi & 0xFFFFFu) << 6)) * QINV;  // bits 26..51
    sv  = (float)(lo & 0x3FFFFFFu) * QINV;           // bits 0..25
}

__global__ __launch_bounds__(256, 4) void sweep_kernel(
    const float* __restrict__ imgs, const uint4* __restrict__ hist2,
    float* __restrict__ out)
{
    // 2048 blocks. XCD swizzle (R13): chunk of 256 logical blocks per XCD,
    // y-major within a strip so adjacent y-groups (sharing boundary row
    // y0+2) are dispatched back-to-back on the same XCD.
    int bid0  = blockIdx.x;
    int L     = ((bid0 & 7) << 8) | (bid0 >> 3);     // bijective on [0,2048)
    int ygrp  = L & 511;
    int strip = L >> 9;                              // 0..3
    int y0    = ygrp << 1;
    int x0    = strip << 8;
    int t     = threadIdx.x;
    int l     = t & 63;
    int g     = t >> 6;                              // group -> batches 2g,2g+1
    int xe    = min(x0 + 256, NYX - 1);              // strip-edge col

    int yr[3] = { y0, min(y0 + 1, NYX - 1), min(y0 + 2, NYX - 1) };

    // hist rows y0, y0+1, cols x0+4l..x0+4l+3 (u64 pairs as uint4), 32 B/lane
    size_t hb0 = ((size_t)y0 * NYX + x0 + 4 * l) >> 1;        // uint4 index
    size_t hb1 = ((size_t)(y0 + 1) * NYX + x0 + 4 * l) >> 1;
    uint4 h0a = hist2[hb0], h0b = hist2[hb0 + 1];
    uint4 h1a = hist2[hb1], h1b = hist2[hb1 + 1];

    // 18 image float4 loads, channel-summed -> S[r][bl][0..3] (cols 4l..4l+3)
    float S[3][2][4];
#pragma unroll
    for (int r = 0; r < 3; ++r) {
#pragma unroll
        for (int bl = 0; bl < 2; ++bl) {
            int b = 2 * g + bl;
            size_t q = (size_t)yr[r] * NYX + x0;
            float4 a0 = ((const float4*)(imgs + (size_t)(b * CH + 0) * NPIX + q))[l];
            float4 a1 = ((const float4*)(imgs + (size_t)(b * CH + 1) * NPIX + q))[l];
            float4 a2 = ((const float4*)(imgs + (size_t)(b * CH + 2) * NPIX + q))[l];
            S[r][bl][0] = a0.x + a1.x + a2.x;
            S[r][bl][1] = a0.y + a1.y + a2.y;
            S[r][bl][2] = a0.z + a1.z + a2.z;
            S[r][bl][3] = a0.w + a1.w + a2.w;
        }
    }

    // strip-edge column (only meaningful for lane 63)
    float edge[3][2] = {{0.f,0.f},{0.f,0.f},{0.f,0.f}};
    if (l == 63) {
#pragma unroll
        for (int r = 0; r < 3; ++r) {
#pragma unroll
            for (int bl = 0; bl < 2; ++bl) {
                int b = 2 * g + bl;
                size_t qe = (size_t)yr[r] * NYX + xe;
                edge[r][bl] = imgs[(size_t)(b * CH + 0) * NPIX + qe] +
                              imgs[(size_t)(b * CH + 1) * NPIX + qe] +
                              imgs[(size_t)(b * CH + 2) * NPIX + qe];
            }
        }
    }

    // next-column S via cross-lane shuffle (lane 63 <- edge)
    float sp[3][2];
#pragma unroll
    for (int r = 0; r < 3; ++r) {
#pragma unroll
        for (int bl = 0; bl < 2; ++bl) {
            float nx = __shfl_down(S[r][bl][0], 1, 64);
            sp[r][bl] = (l == 63) ? edge[r][bl] : nx;
        }
    }

    // decode 8 hist cells once (batch-independent)
    float cnt[2][4], su[2][4], sv[2][4];
    dec_cell(h0a.x, h0a.y, cnt[0][0], su[0][0], sv[0][0]);
    dec_cell(h0a.z, h0a.w, cnt[0][1], su[0][1], sv[0][1]);
    dec_cell(h0b.x, h0b.y, cnt[0][2], su[0][2], sv[0][2]);
    dec_cell(h0b.z, h0b.w, cnt[0][3], su[0][3], sv[0][3]);
    dec_cell(h1a.x, h1a.y, cnt[1][0], su[1][0], sv[1][0]);
    dec_cell(h1a.z, h1a.w, cnt[1][1], su[1][1], sv[1][1]);
    dec_cell(h1b.x, h1b.y, cnt[1][2], su[1][2], sv[1][2]);
    dec_cell(h1b.z, h1b.w, cnt[1][3], su[1][3], sv[1][3]);

    // 16 cells per batch-lane: rows k=0,1 x cols j=0..3 x batches bl=0,1
    float acc0[2] = {0.f, 0.f}, acc1[2] = {0.f, 0.f};
#pragma unroll
    for (int bl = 0; bl < 2; ++bl) {
#pragma unroll
        for (int k = 0; k < 2; ++k) {
#pragma unroll
            for (int j = 0; j < 4; ++j) {
                float c00 = S[k][bl][j];
                float c01 = (j < 3) ? S[k][bl][j + 1] : sp[k][bl];
                float c10 = S[k + 1][bl][j];
                float c11 = (j < 3) ? S[k + 1][bl][j + 1] : sp[k + 1][bl];
                float Dy = c10 - c00;
                float Dx = c01 - c00;
                float Mm = (c11 - c01) - Dy;
                acc0[bl] += cnt[k][j] * Dy + su[k][j] * Mm;
                acc1[bl] += cnt[k][j] * Dx + sv[k][j] * Mm;
            }
        }
    }

    // wave reduction (wave g owns out[4g..4g+3])
#pragma unroll
    for (int off = 32; off > 0; off >>= 1) {
        acc0[0] += __shfl_down(acc0[0], off, 64);
        acc1[0] += __shfl_down(acc1[0], off, 64);
        acc0[1] += __shfl_down(acc0[1], off, 64);
        acc1[1] += __shfl_down(acc1[1], off, 64);
    }

    // block epilogue: ONE 16-lane atomic instruction per block (R18 pattern;
    // 2048 packets total on the shared out-line, vs R19's 32768)
    __shared__ float sred[4][4];
    if (l == 0) {
        sred[g][0] = acc0[0];                        // out[4g+0]
        sred[g][1] = acc1[0];                        // out[4g+1]
        sred[g][2] = acc0[1];                        // out[4g+2]
        sred[g][3] = acc1[1];                        // out[4g+3]
    }
    __syncthreads();
    if (t < 16)
        atomicAdd(&out[t], sred[t >> 2][t & 3]);
}

// ---- fallback (round-1 unsorted path) if ws is too small ----
__global__ void zero_out_kernel(float* __restrict__ out) {
    int i = threadIdx.x;
    if (i < 16) out[i] = 0.0f;
}

__global__ __launch_bounds__(256) void interp_grad_kernel(
    const float* __restrict__ imgs, const float* __restrict__ z,
    float* __restrict__ out, int npts)
{
    int p = blockIdx.x * blockDim.x + threadIdx.x;
    float acc0[BATCH];
    float acc1[BATCH];
#pragma unroll
    for (int b = 0; b < BATCH; ++b) { acc0[b] = 0.0f; acc1[b] = 0.0f; }
    if (p < npts) {
        float2 zz = ((const float2*)z)[p];
        float x0y = zz.x * (float)(NYX - 1);
        float x0x = zz.y * (float)(NYX - 1);
        bool oob = (x0y < 0.0f) || (x0y > (float)(NYX - 1)) ||
                   (x0x < 0.0f) || (x0x > (float)(NYX - 1));
        if (!oob) {
            int yg = min((int)floorf(x0y), NYX - 2);
            int xg = min((int)floorf(x0x), NYX - 2);
            float fy = (float)yg - x0y;
            float fx = (float)xg - x0x;
            const float* base = imgs + (size_t)yg * NYX + xg;
#pragma unroll
            for (int b = 0; b < BATCH; ++b) {
#pragma unroll
                for (int c = 0; c < CH; ++c) {
                    const float* pl = base + (size_t)(b * CH + c) * (size_t)NPIX;
                    float g00 = pl[0];
                    float g01 = pl[1];
                    float g10 = pl[NYX];
                    float g11 = pl[NYX + 1];
                    float a1 = g10 - g00;
                    float a2 = g11 - g01;
                    float a3 = g01 - g00;
                    float d  = a1 - a2;
                    acc0[b] += d * fx + a1;
                    acc1[b] += d * fy + a3;
                }
            }
        }
    }
#pragma unroll
    for (int b = 0; b < BATCH; ++b) {
#pragma unroll
        for (int off = 32; off > 0; off >>= 1) {
            acc0[b] += __shfl_down(acc0[b], off, 64);
            acc1[b] += __shfl_down(acc1[b], off, 64);
        }
    }
    __shared__ float sred2[4][16];
    int lane = threadIdx.x & 63;
    int wave = threadIdx.x >> 6;
    if (lane == 0) {
#pragma unroll
        for (int b = 0; b < BATCH; ++b) {
            sred2[wave][2 * b + 0] = acc0[b];
            sred2[wave][2 * b + 1] = acc1[b];
        }
    }
    __syncthreads();
    if (threadIdx.x < 16) {
        float s = sred2[0][threadIdx.x] + sred2[1][threadIdx.x] +
                  sred2[2][threadIdx.x] + sred2[3][threadIdx.x];
        atomicAdd(&out[threadIdx.x], s);
    }
}

extern "C" void kernel_launch(void* const* d_in, const int* in_sizes, int n_in,
                              void* d_out, int out_size, void* d_ws, size_t ws_size,
                              hipStream_t stream) {
    const float* imgs = (const float*)d_in[0];
    const float* z    = (const float*)d_in[1];
    float* out        = (float*)d_out;
    int npts = in_sizes[1] / 2;

    size_t ws_need = (size_t)NPIX * 8;               // 8 MB u64 hist

    if (ws_size < ws_need) {
        int blocks = (npts + 255) / 256;
        zero_out_kernel<<<1, 64, 0, stream>>>(out);
        interp_grad_kernel<<<blocks, 256, 0, stream>>>(imgs, z, out, npts);
        return;
    }

    unsigned long long* hist = (unsigned long long*)d_ws;
    int npairs = npts >> 1;
    int hist_blocks = (npairs + 256) / 256;          // covers odd-tail thread

    hipMemsetAsync(d_ws, 0, ws_need, stream);        // stream-capturable
    hist_kernel<<<hist_blocks, 256, 0, stream>>>(z, hist, out, npts);
    sweep_kernel<<<2048, 256, 0, stream>>>(imgs, (const uint4*)hist, out);
}